// Round 12
// baseline (233.950 us; speedup 1.0000x reference)
//
#include <hip/hip_runtime.h>
#include <hip/hip_bf16.h>

#define Bz 4
#define Sz 2048
#define Dz 1024
#define Hz 16
#define DHz 64

typedef __bf16 bf16x8 __attribute__((ext_vector_type(8)));
typedef float f32x4 __attribute__((ext_vector_type(4)));
typedef short s16x4 __attribute__((ext_vector_type(4)));
typedef short s16x8 __attribute__((ext_vector_type(8)));
typedef unsigned short u16x4 __attribute__((ext_vector_type(4)));

// 0.125 * log2(e): folded into Q at the QKV-GEMM epilogue so attention's
// scores arrive pre-scaled for exp2-domain softmax.
#define SCQF 0.18033688011112042f

// Single fused fp32->bf16 cast for x (TOK elems) + 4 weight matrices, all
// writing the contiguous ws region starting at xb (wqb = xb + TOK).
__global__ __launch_bounds__(256) void cvt_all(const float* __restrict__ x,
                                               const float* __restrict__ w0, const float* __restrict__ w1,
                                               const float* __restrict__ w2, const float* __restrict__ w3,
                                               __hip_bfloat16* __restrict__ dst) {
    constexpr int TOK = Bz * Sz * Dz;   // 8,388,608
    constexpr int WEL = Dz * Dz;        // 1<<20
    int i = (blockIdx.x * 256 + threadIdx.x) * 4;
    const float* src;
    if (i < TOK) {
        src = x + i;
    } else {
        const int jj = i - TOK;
        const int which = jj >> 20;
        const float* w = (which == 0) ? w0 : (which == 1) ? w1 : (which == 2) ? w2 : w3;
        src = w + (jj & (WEL - 1));
    }
    float4 f = *reinterpret_cast<const float4*>(src);
    dst[i + 0] = __float2bfloat16(f.x);
    dst[i + 1] = __float2bfloat16(f.y);
    dst[i + 2] = __float2bfloat16(f.z);
    dst[i + 3] = __float2bfloat16(f.w);
}

// async global -> LDS, 16 bytes per lane; LDS dest = uniform base + lane*16.
__device__ __forceinline__ void gl2lds16(const __hip_bfloat16* g, __hip_bfloat16* l) {
    __builtin_amdgcn_global_load_lds(
        (const __attribute__((address_space(1))) void*)g,
        (__attribute__((address_space(3))) void*)l, 16, 0, 0);
}

// generic pointer -> 32-bit LDS byte offset (for inline-asm DS ops)
__device__ __forceinline__ unsigned ldsaddr(const void* p) {
    return (unsigned)(size_t)(const __attribute__((address_space(3))) void*)p;
}

// Shared 128x128 GEMM block body — BK=64 + XOR-swizzled LDS (verified rounds
// 6/8: qkv ~66us, 0 bank conflicts). Rounds 9/10 pipeline attempts (2-phase
// drain / counted-vmcnt ring) both regressed (92 / 80us) -> this 2-phase BK=64
// body is this session's declared GEMM ceiling. (Round-11 qkv read 80us with
// identical source vs 66 in round 8: attributed to container/clock variance +
// co-compile regalloc perturbation, not chased.)
// C-write modes: 0 = row-major [M][N]; 1 = K head-major [bh][s][64];
// 2 = V 16-wide panels [bh][dh>>4][s][16]. SCQ: scale by SCQF before bf16 cast.
template <int N, int K, typename OT, int MODE, bool SCQ = false>
__device__ __forceinline__ void gemm128_body(const __hip_bfloat16* __restrict__ A,
                                             const __hip_bfloat16* __restrict__ W,
                                             OT* __restrict__ C, int bm, int bn,
                                             __hip_bfloat16* As, __hip_bfloat16* Bs) {
    const int tid  = threadIdx.x;
    const int wid  = tid >> 6;
    const int lane = tid & 63;
    const int quad = lane >> 4;
    const int l16  = lane & 15;
    const int wr = wid >> 1, wc = wid & 1;

    // staging: wave wid owns rows [wid*32, +32) of each tile, 4 calls x 8 rows.
    const int rlo = lane >> 3;                   // row within 8-row call
    const int xel = ((lane & 7) ^ rlo) * 8;      // pre-swizzled element offset
    const __hip_bfloat16* gA = A + (size_t)(bm * 128 + wid * 32 + rlo) * K + xel;
    const __hip_bfloat16* gB = W + (size_t)(bn * 128 + wid * 32 + rlo) * K + xel;
    __hip_bfloat16* lA = &As[(wid * 32) * 64];
    __hip_bfloat16* lB = &Bs[(wid * 32) * 64];

    const unsigned sw = (unsigned)((l16 & 7) << 4);  // read-side XOR (bytes)
    const char* Ap = (const char*)As;
    const char* Bp = (const char*)Bs;

    f32x4 acc[4][4] = {};

    for (int k0 = 0; k0 < K; k0 += 64) {
        __syncthreads();
#pragma unroll
        for (int c = 0; c < 4; ++c) {
            gl2lds16(gA + (size_t)(c * 8) * K + k0, lA + (c * 8) * 64);
            gl2lds16(gB + (size_t)(c * 8) * K + k0, lB + (c * 8) * 64);
        }
        __syncthreads();

#pragma unroll
        for (int kk = 0; kk < 2; ++kk) {
            bf16x8 af[4], bf[4];
#pragma unroll
            for (int mi = 0; mi < 4; ++mi)
                af[mi] = *reinterpret_cast<const bf16x8*>(
                    Ap + (wr * 64 + mi * 16 + l16) * 128 + ((kk * 64 + quad * 16) ^ sw));
#pragma unroll
            for (int ni = 0; ni < 4; ++ni)
                bf[ni] = *reinterpret_cast<const bf16x8*>(
                    Bp + (wc * 64 + ni * 16 + l16) * 128 + ((kk * 64 + quad * 16) ^ sw));
#pragma unroll
            for (int mi = 0; mi < 4; ++mi)
#pragma unroll
                for (int ni = 0; ni < 4; ++ni)
                    acc[mi][ni] = __builtin_amdgcn_mfma_f32_16x16x32_bf16(af[mi], bf[ni], acc[mi][ni], 0, 0, 0);
        }
    }

#pragma unroll
    for (int mi = 0; mi < 4; ++mi)
#pragma unroll
        for (int ni = 0; ni < 4; ++ni) {
            const int row0 = bm * 128 + wr * 64 + mi * 16 + quad * 4;
            const int col  = bn * 128 + wc * 64 + ni * 16 + l16;
#pragma unroll
            for (int r = 0; r < 4; ++r) {
                const int row = row0 + r;
                float v = acc[mi][ni][r];
                if constexpr (SCQ) v *= SCQF;
                if constexpr (MODE == 0) {
                    if constexpr (__is_same(OT, float))
                        C[(size_t)row * N + col] = v;
                    else
                        C[(size_t)row * N + col] = __float2bfloat16(v);
                } else if constexpr (MODE == 1) {
                    const int bh = (row >> 11) * Hz + (col >> 6);
                    C[(size_t)bh * (Sz * DHz) + (size_t)(row & 2047) * 64 + (col & 63)] =
                        __float2bfloat16(v);
                } else {
                    const int bh = (row >> 11) * Hz + (col >> 6);
                    C[(size_t)bh * (Sz * DHz) + (size_t)((col >> 4) & 3) * (Sz * 16) +
                      (size_t)(row & 2047) * 16 + (col & 15)] = __float2bfloat16(v);
                }
            }
        }
}

// Final GEMM with T1 XCD-chunk swizzle: each XCD gets a contiguous chunk of
// (bm,bn) tiles -> A chunk 2MB + wo 2MB fit its private 4MB L2.
template <int M, int N, int K, typename OT>
__global__ __launch_bounds__(256) void gemm128(const __hip_bfloat16* __restrict__ A,
                                               const __hip_bfloat16* __restrict__ W,
                                               OT* __restrict__ C) {
    __shared__ __hip_bfloat16 As[128 * 64];
    __shared__ __hip_bfloat16 Bs[128 * 64];
    constexpr int NB = N / 128;
    constexpr int NWG = (M / 128) * NB;          // 512, %8==0 -> bijective
    const int bid = blockIdx.x;
    const int swz = (bid & 7) * (NWG / 8) + (bid >> 3);
    gemm128_body<N, K, OT, 0>(A, W, C, swz / NB, swz % NB, As, Bs);
}

// Fused QKV with T1 XCD-chunk swizzle: semantic index s = rem*3 + which keeps
// the 3 GEMMs of one A-tile adjacent; chunking gives each XCD 64 consecutive
// (bm,bn) tiles (A chunk 8 panels = 2MB -> L2-resident per XCD).
template <int M, int K>
__global__ __launch_bounds__(256) void gemm_qkv(const __hip_bfloat16* __restrict__ A,
                                                const __hip_bfloat16* __restrict__ W0,
                                                const __hip_bfloat16* __restrict__ W1,
                                                const __hip_bfloat16* __restrict__ W2,
                                                __hip_bfloat16* __restrict__ C0,
                                                __hip_bfloat16* __restrict__ C1,
                                                __hip_bfloat16* __restrict__ C2) {
    __shared__ __hip_bfloat16 As[128 * 64];
    __shared__ __hip_bfloat16 Bs[128 * 64];
    constexpr int NB = Dz / 128;
    constexpr int NWG = 3 * (M / 128) * NB;      // 1536, %8==0 -> bijective
    const int bid = blockIdx.x;
    const int s   = (bid & 7) * (NWG / 8) + (bid >> 3);
    const int which = s % 3;
    const int rem   = s / 3;
    const int bm = rem / NB, bn = rem % NB;
    if (which == 0)      gemm128_body<Dz, K, __hip_bfloat16, 0, true>(A, W0, C0, bm, bn, As, Bs);
    else if (which == 1) gemm128_body<Dz, K, __hip_bfloat16, 1>(A, W1, C1, bm, bn, As, Bs);
    else                 gemm128_body<Dz, K, __hip_bfloat16, 2>(A, W2, C2, bm, bn, As, Bs);
}

// concat two 4x bf16 fragments into a K=32 8x bf16 fragment (register-only).
__device__ __forceinline__ bf16x8 cat8(s16x4 a, s16x4 b) {
    s16x8 t = __builtin_shufflevector(a, b, 0, 1, 2, 3, 4, 5, 6, 7);
    union { s16x8 s; bf16x8 h; } u; u.s = t; return u.h;
}

__device__ __forceinline__ f32x4 mfma32bf(bf16x8 a, bf16x8 b, f32x4 c) {
    return __builtin_amdgcn_mfma_f32_16x16x32_bf16(a, b, c, 0, 0, 0);
}

// HW transpose read: lane reads 8 CONSECUTIVE bytes at its own address; the
// transpose is a cross-lane exchange within each 16-lane group. With linear
// addresses base + lane*8 over a [16key][16dh] 512B subtile: lane(quad,l16)
// elem j = tile[quad*4+j][l16] (m156's layout; verified round 4).
#define TRD(i, off) \
    asm volatile("ds_read_b64_tr_b16 %0, %1 offset:" off : "=v"(vf[i]) : "v"(va))

// MFMA flash attention v10 — v9 (K=32 PV, verified) + SHARED K-tile stream:
//  v7/v9 ran the paired q-blocks as two sequential passes, staging the
//  overlapping low-index K/V tiles twice (33 stagings/block). v10 runs ONE
//  K-tile loop t=0..31-pair: q-block B=31-pair computed every tile, q-block
//  A=pair while t<=pair (block-uniform guard). Stagings 33 -> 32-pair
//  (avg 24.5, -26%); the 16 TR reads + 8 K-fragment LDS reads per tile are
//  SHARED by both q-blocks (V^T fragments are q-independent); dual iterations
//  give the softmax chain 2x ILP (T15 mechanism). Per-CU load stays balanced:
//  co-resident blocks have adjacent pair values. Per-q-block math is v9's,
//  duplicated. TR-window discipline unchanged.
__global__ __launch_bounds__(256, 4) void attn_mfma10(const __hip_bfloat16* __restrict__ Q,
                                                      const __hip_bfloat16* __restrict__ Kh,
                                                      const __hip_bfloat16* __restrict__ Vh,
                                                      __hip_bfloat16* __restrict__ O) {
    __shared__ __hip_bfloat16 Ks[2][64 * 64];   // [key][dh], rows XOR-swizzled
    __shared__ __hip_bfloat16 Vs[2][64 * 64];   // [dh>>4][key][16] panels

    const int tid  = threadIdx.x;
    const int wid  = tid >> 6;
    const int lane = tid & 63;
    const int quad = lane >> 4;
    const int l16  = lane & 15;

    // XCD-local mapping: all 16 pair-blocks of a (b,h) share blockIdx%8 -> same XCD L2.
    const int xcd  = blockIdx.x & 7;
    const int j    = blockIdx.x >> 3;            // 0..127
    const int bh   = xcd * 8 + (j >> 4);         // 0..63
    const int pair = j & 15;
    const int h    = bh & 15;
    const int b    = bh >> 4;
    const size_t baseQ = (size_t)b * Sz * Dz + (size_t)h * DHz;   // Q/O row-major
    const size_t kvb   = (size_t)bh * (Sz * DHz);                 // K/V head-major

    // staging lane constants
    const int rlo = lane >> 3;                   // K: row-in-call
    const int xel = ((lane & 7) ^ rlo) * 8;      // K: pre-swizzled element offset

    auto stage = [&](int kn, int bf_) {
#pragma unroll
        for (int c = 0; c < 2; ++c) {
            // K: wave wid stages rows [wid*16+c*8, +8): 1KB coalesced, source pre-swizzled
            gl2lds16(Kh + kvb + (size_t)(kn + wid * 16 + c * 8 + rlo) * 64 + xel,
                     &Ks[bf_][(wid * 16 + c * 8) * 64]);
            // V: wave wid stages panel dh-group wid, keys [kn+c*32, +32): 1KB coalesced
            gl2lds16(Vh + kvb + (size_t)wid * (Sz * 16) + (size_t)(kn + c * 32 + (lane >> 1)) * 16 + (lane & 1) * 8,
                     &Vs[bf_][wid * 1024 + c * 512]);
        }
    };

    const unsigned vb0 = ldsaddr(&Vs[0][0]) + lane * 8;   // linear per-lane TR addr
    const unsigned sw  = (l16 & 7) << 4;         // read-side XOR for K rows

    union { s16x8 s; bf16x8 h; } onesu;
#pragma unroll
    for (int i = 0; i < 8; ++i) onesu.s[i] = (short)0x3F80;  // bf16 1.0 x8
    const bf16x8 ones8 = onesu.h;

    const int qbA = pair;                        // 0..15  (conditional, shorter)
    const int qbB = 31 - pair;                   // 16..31 (unconditional, longer)
    const int q0A = qbA * 64 + wid * 16;
    const int q0B = qbB * 64 + wid * 16;
    const int niter = qbB + 1;                   // 17..32 K-tiles

    const __hip_bfloat16* qpA = Q + baseQ + (size_t)(q0A + l16) * Dz + quad * 8;
    const __hip_bfloat16* qpB = Q + baseQ + (size_t)(q0B + l16) * Dz + quad * 8;
    const bf16x8 qfA0 = *reinterpret_cast<const bf16x8*>(qpA);
    const bf16x8 qfA1 = *reinterpret_cast<const bf16x8*>(qpA + 32);
    const bf16x8 qfB0 = *reinterpret_cast<const bf16x8*>(qpB);
    const bf16x8 qfB1 = *reinterpret_cast<const bf16x8*>(qpB + 32);

    float mA = -1e30f, mB = -1e30f;
    f32x4 otA[4] = {}, otB[4] = {};
    f32x4 laccA = {}, laccB = {};

    int buf = 0;
    stage(0, 0);
    __syncthreads();

#pragma unroll 1
    for (int t = 0; t < niter; ++t) {
        const int k0 = t * 64;
        const bool actA = (t <= qbA);            // block-uniform

        // QK for both q-blocks from the SHARED Ks[buf] (8 ds_read_b128 total)
        f32x4 stB[4] = {};
        f32x4 stA[4] = {};
        {
            const char* Kp = (const char*)&Ks[buf][0];
#pragma unroll
            for (int s = 0; s < 4; ++s) {
                const int rb = (s * 16 + l16) * 128;
                const bf16x8 a0 = *reinterpret_cast<const bf16x8*>(Kp + rb + ((quad * 16) ^ sw));
                const bf16x8 a1 = *reinterpret_cast<const bf16x8*>(Kp + rb + ((quad * 16 + 64) ^ sw));
                stB[s] = mfma32bf(a0, qfB0, stB[s]);
                stB[s] = mfma32bf(a1, qfB1, stB[s]);
                if (actA) {
                    stA[s] = mfma32bf(a0, qfA0, stA[s]);
                    stA[s] = mfma32bf(a1, qfA1, stA[s]);
                }
            }
        }

        // stage next tile into buf^1 (released by prev iter's syncthreads)
        if (t + 1 < niter) stage(k0 + 64, buf ^ 1);

        // ---------- softmax A (complete to pwA, freeing temporaries) ----------
        bf16x8 pwA01 = {}, pwA23 = {};
        if (actA) {
            float sv[16];
            if (t == qbA) {                      // A's diagonal tile
                const int qrow = q0A + l16;
#pragma unroll
                for (int s = 0; s < 4; ++s)
#pragma unroll
                    for (int r = 0; r < 4; ++r) {
                        const int key = k0 + s * 16 + quad * 4 + r;
                        sv[s * 4 + r] = (key <= qrow) ? stA[s][r] : -1e30f;
                    }
            } else {
#pragma unroll
                for (int s = 0; s < 4; ++s)
#pragma unroll
                    for (int r = 0; r < 4; ++r) sv[s * 4 + r] = stA[s][r];
            }
            const float p0 = fmaxf(fmaxf(sv[0],  sv[1]),  sv[2]);
            const float p1 = fmaxf(fmaxf(sv[3],  sv[4]),  sv[5]);
            const float p2 = fmaxf(fmaxf(sv[6],  sv[7]),  sv[8]);
            const float p3 = fmaxf(fmaxf(sv[9],  sv[10]), sv[11]);
            const float p4 = fmaxf(fmaxf(sv[12], sv[13]), sv[14]);
            const float p5 = fmaxf(fmaxf(p0, p1), p2);
            float tmax = fmaxf(fmaxf(fmaxf(p5, p3), p4), sv[15]);
            tmax = fmaxf(tmax, __shfl_xor(tmax, 16, 64));
            tmax = fmaxf(tmax, __shfl_xor(tmax, 32, 64));
            const float mnew = fmaxf(mA, tmax);
            const bool  skip = __all(tmax <= mA);
            if (!skip) {
                const float alpha = __builtin_amdgcn_exp2f(mA - mnew);
                mA = mnew;
#pragma unroll
                for (int s = 0; s < 4; ++s) otA[s] *= alpha;
                laccA[0] *= alpha;
            }
            float pv[16];
#pragma unroll
            for (int i = 0; i < 16; ++i) pv[i] = __builtin_amdgcn_exp2f(sv[i] - mA);
            union { s16x8 s; bf16x8 h; } u01, u23;
#pragma unroll
            for (int r = 0; r < 4; ++r) {
                union { __hip_bfloat16 hh; short uu; } c0, c1, c2, c3;
                c0.hh = __float2bfloat16(pv[r]);
                c1.hh = __float2bfloat16(pv[4 + r]);
                c2.hh = __float2bfloat16(pv[8 + r]);
                c3.hh = __float2bfloat16(pv[12 + r]);
                u01.s[r] = c0.uu; u01.s[4 + r] = c1.uu;
                u23.s[r] = c2.uu; u23.s[4 + r] = c3.uu;
            }
            pwA01 = u01.h; pwA23 = u23.h;
            laccA = mfma32bf(ones8, pwA01, laccA);
            laccA = mfma32bf(ones8, pwA23, laccA);
        }

        // ---------- softmax B (pv kept; pack overlaps TR batch 1) ----------
        float svB[16];
        if (t == qbB) {                          // B's diagonal tile (last iter)
            const int qrow = q0B + l16;
#pragma unroll
            for (int s = 0; s < 4; ++s)
#pragma unroll
                for (int r = 0; r < 4; ++r) {
                    const int key = k0 + s * 16 + quad * 4 + r;
                    svB[s * 4 + r] = (key <= qrow) ? stB[s][r] : -1e30f;
                }
        } else {
#pragma unroll
            for (int s = 0; s < 4; ++s)
#pragma unroll
                for (int r = 0; r < 4; ++r) svB[s * 4 + r] = stB[s][r];
        }
        {
            const float p0 = fmaxf(fmaxf(svB[0],  svB[1]),  svB[2]);
            const float p1 = fmaxf(fmaxf(svB[3],  svB[4]),  svB[5]);
            const float p2 = fmaxf(fmaxf(svB[6],  svB[7]),  svB[8]);
            const float p3 = fmaxf(fmaxf(svB[9],  svB[10]), svB[11]);
            const float p4 = fmaxf(fmaxf(svB[12], svB[13]), svB[14]);
            const float p5 = fmaxf(fmaxf(p0, p1), p2);
            float tmax = fmaxf(fmaxf(fmaxf(p5, p3), p4), svB[15]);
            tmax = fmaxf(tmax, __shfl_xor(tmax, 16, 64));
            tmax = fmaxf(tmax, __shfl_xor(tmax, 32, 64));
            const float mnew = fmaxf(mB, tmax);
            const bool  skip = __all(tmax <= mB);
            if (!skip) {
                const float alpha = __builtin_amdgcn_exp2f(mB - mnew);
                mB = mnew;
#pragma unroll
                for (int s = 0; s < 4; ++s) otB[s] *= alpha;
                laccB[0] *= alpha;
            }
        }
        float pvB[16];
#pragma unroll
        for (int i = 0; i < 16; ++i) pvB[i] = __builtin_amdgcn_exp2f(svB[i] - mB);

        // ---- lgkm-clean window: TR batch 1 overlaps B-pack + l-MFMAs ----
        s16x4 vf[16];
        const unsigned va = vb0 + (unsigned)(buf << 13);
        TRD(0, "0");    TRD(1, "512");  TRD(2, "1024"); TRD(3, "1536");
        TRD(4, "2048"); TRD(5, "2560"); TRD(6, "3072"); TRD(7, "3584");

        bf16x8 pwB01, pwB23;
        {
            union { s16x8 s; bf16x8 h; } u01, u23;
#pragma unroll
            for (int r = 0; r < 4; ++r) {
                union { __hip_bfloat16 hh; short uu; } c0, c1, c2, c3;
                c0.hh = __float2bfloat16(pvB[r]);
                c1.hh = __float2bfloat16(pvB[4 + r]);
                c2.hh = __float2bfloat16(pvB[8 + r]);
                c3.hh = __float2bfloat16(pvB[12 + r]);
                u01.s[r] = c0.uu; u01.s[4 + r] = c1.uu;
                u23.s[r] = c2.uu; u23.s[4 + r] = c3.uu;
            }
            pwB01 = u01.h; pwB23 = u23.h;
        }
        laccB = mfma32bf(ones8, pwB01, laccB);
        laccB = mfma32bf(ones8, pwB23, laccB);

        asm volatile("s_waitcnt lgkmcnt(0)" ::: "memory");
        __builtin_amdgcn_sched_barrier(0);
        TRD(8,  "4096"); TRD(9,  "4608"); TRD(10, "5120"); TRD(11, "5632");
        TRD(12, "6144"); TRD(13, "6656"); TRD(14, "7168"); TRD(15, "7680");

        // PV sd0/sd1 for both q-blocks (shared vf; covers TR batch 2 latency)
        otB[0] = mfma32bf(cat8(vf[0], vf[1]), pwB01, otB[0]);
        otB[0] = mfma32bf(cat8(vf[2], vf[3]), pwB23, otB[0]);
        otB[1] = mfma32bf(cat8(vf[4], vf[5]), pwB01, otB[1]);
        otB[1] = mfma32bf(cat8(vf[6], vf[7]), pwB23, otB[1]);
        if (actA) {
            otA[0] = mfma32bf(cat8(vf[0], vf[1]), pwA01, otA[0]);
            otA[0] = mfma32bf(cat8(vf[2], vf[3]), pwA23, otA[0]);
            otA[1] = mfma32bf(cat8(vf[4], vf[5]), pwA01, otA[1]);
            otA[1] = mfma32bf(cat8(vf[6], vf[7]), pwA23, otA[1]);
        }

        asm volatile("s_waitcnt lgkmcnt(0)" ::: "memory");
        __builtin_amdgcn_sched_barrier(0);
        otB[2] = mfma32bf(cat8(vf[8],  vf[9]),  pwB01, otB[2]);
        otB[2] = mfma32bf(cat8(vf[10], vf[11]), pwB23, otB[2]);
        otB[3] = mfma32bf(cat8(vf[12], vf[13]), pwB01, otB[3]);
        otB[3] = mfma32bf(cat8(vf[14], vf[15]), pwB23, otB[3]);
        if (actA) {
            otA[2] = mfma32bf(cat8(vf[8],  vf[9]),  pwA01, otA[2]);
            otA[2] = mfma32bf(cat8(vf[10], vf[11]), pwA23, otA[2]);
            otA[3] = mfma32bf(cat8(vf[12], vf[13]), pwA01, otA[3]);
            otA[3] = mfma32bf(cat8(vf[14], vf[15]), pwA23, otA[3]);
        }

        __syncthreads();   // drains our glds (vmcnt 0) + releases buffers
        buf ^= 1;
    }

    // epilogues: lane holds O^T[dh=sd*16+quad*4+r][q=l16]; lacc[0] own-lane denom.
    {
        const float linv = 1.f / laccA[0];
        __hip_bfloat16* op = O + baseQ + (size_t)(q0A + l16) * Dz + quad * 4;
#pragma unroll
        for (int sd = 0; sd < 4; ++sd) {
            u16x4 w;
#pragma unroll
            for (int r = 0; r < 4; ++r) {
                union { __hip_bfloat16 hh; unsigned short uu; } cv;
                cv.hh = __float2bfloat16(otA[sd][r] * linv);
                w[r] = cv.uu;
            }
            *reinterpret_cast<u16x4*>(op + sd * 16) = w;
        }
    }
    {
        const float linv = 1.f / laccB[0];
        __hip_bfloat16* op = O + baseQ + (size_t)(q0B + l16) * Dz + quad * 4;
#pragma unroll
        for (int sd = 0; sd < 4; ++sd) {
            u16x4 w;
#pragma unroll
            for (int r = 0; r < 4; ++r) {
                union { __hip_bfloat16 hh; unsigned short uu; } cv;
                cv.hh = __float2bfloat16(otB[sd][r] * linv);
                w[r] = cv.uu;
            }
            *reinterpret_cast<u16x4*>(op + sd * 16) = w;
        }
    }
}

extern "C" void kernel_launch(void* const* d_in, const int* in_sizes, int n_in,
                              void* d_out, int out_size, void* d_ws, size_t ws_size,
                              hipStream_t stream) {
    // Inputs fp32, output fp32. Internal compute bf16.
    const float* x  = (const float*)d_in[0];
    const float* wq = (const float*)d_in[1];
    const float* wk = (const float*)d_in[2];
    const float* wv = (const float*)d_in[3];
    const float* wo = (const float*)d_in[4];
    float* out = (float*)d_out;

    constexpr int TOK = Bz * Sz * Dz;   // 8,388,608
    constexpr int WEL = Dz * Dz;        // 1,048,576

    // ws: xb | wqb | wkb | wvb | wob | Qb | Kh (56 MB). Vh in d_out scratch; Ob aliases xb.
    __hip_bfloat16* xb  = (__hip_bfloat16*)d_ws;
    __hip_bfloat16* wqb = xb  + TOK;
    __hip_bfloat16* wkb = wqb + WEL;
    __hip_bfloat16* wvb = wkb + WEL;
    __hip_bfloat16* wob = wvb + WEL;
    __hip_bfloat16* Qb  = wob + WEL;
    __hip_bfloat16* Kh  = Qb + TOK;
    __hip_bfloat16* Vh  = (__hip_bfloat16*)d_out;  // dead before final GEMM overwrites d_out
    __hip_bfloat16* Ob  = xb;                      // x dead after QKV GEMM

    cvt_all<<<(TOK + 4 * WEL) / 4 / 256, 256, 0, stream>>>(x, wq, wk, wv, wo, xb);

    constexpr int M = Bz * Sz;                       // 8192
    constexpr int GB = (M / 128) * (Dz / 128);       // 512

    gemm_qkv<M, Dz><<<3 * GB, 256, 0, stream>>>(xb, wqb, wkb, wvb, Qb, Kh, Vh);

    const int ATTN_BLOCKS = Bz * Hz * 16;            // 1024 (paired 64-row q-blocks)
    attn_mfma10<<<ATTN_BLOCKS, 256, 0, stream>>>(Qb, Kh, Vh, Ob);

    gemm128<M, Dz, Dz, float><<<GB, 256, 0, stream>>>(Ob, wob, out);
}

// Round 13
// 231.232 us; speedup vs baseline: 1.0118x; 1.0118x over previous
//
#include <hip/hip_runtime.h>
#include <hip/hip_bf16.h>

#define Bz 4
#define Sz 2048
#define Dz 1024
#define Hz 16
#define DHz 64

typedef __bf16 bf16x8 __attribute__((ext_vector_type(8)));
typedef float f32x4 __attribute__((ext_vector_type(4)));
typedef short s16x4 __attribute__((ext_vector_type(4)));
typedef short s16x8 __attribute__((ext_vector_type(8)));
typedef unsigned short u16x4 __attribute__((ext_vector_type(4)));

// 0.125 * log2(e): folded into Q at the QKV-GEMM epilogue so attention's
// scores arrive pre-scaled for exp2-domain softmax.
#define SCQF 0.18033688011112042f

// Single fused fp32->bf16 cast for x (TOK elems) + 4 weight matrices, all
// writing the contiguous ws region starting at xb (wqb = xb + TOK).
__global__ __launch_bounds__(256) void cvt_all(const float* __restrict__ x,
                                               const float* __restrict__ w0, const float* __restrict__ w1,
                                               const float* __restrict__ w2, const float* __restrict__ w3,
                                               __hip_bfloat16* __restrict__ dst) {
    constexpr int TOK = Bz * Sz * Dz;   // 8,388,608
    constexpr int WEL = Dz * Dz;        // 1<<20
    int i = (blockIdx.x * 256 + threadIdx.x) * 4;
    const float* src;
    if (i < TOK) {
        src = x + i;
    } else {
        const int jj = i - TOK;
        const int which = jj >> 20;
        const float* w = (which == 0) ? w0 : (which == 1) ? w1 : (which == 2) ? w2 : w3;
        src = w + (jj & (WEL - 1));
    }
    float4 f = *reinterpret_cast<const float4*>(src);
    dst[i + 0] = __float2bfloat16(f.x);
    dst[i + 1] = __float2bfloat16(f.y);
    dst[i + 2] = __float2bfloat16(f.z);
    dst[i + 3] = __float2bfloat16(f.w);
}

// async global -> LDS, 16 bytes per lane; LDS dest = uniform base + lane*16.
__device__ __forceinline__ void gl2lds16(const __hip_bfloat16* g, __hip_bfloat16* l) {
    __builtin_amdgcn_global_load_lds(
        (const __attribute__((address_space(1))) void*)g,
        (__attribute__((address_space(3))) void*)l, 16, 0, 0);
}

// generic pointer -> 32-bit LDS byte offset (for inline-asm DS ops)
__device__ __forceinline__ unsigned ldsaddr(const void* p) {
    return (unsigned)(size_t)(const __attribute__((address_space(3))) void*)p;
}

// Shared 128x128 GEMM block body — BK=64 + XOR-swizzled LDS (verified rounds
// 6/8: qkv ~66us, 0 bank conflicts). Rounds 9/10 pipeline attempts (2-phase
// drain / counted-vmcnt ring) both regressed (92 / 80us) -> this 2-phase BK=64
// body is this session's declared GEMM ceiling. (Rounds 11/12 read qkv at
// ~80-83us with byte-identical source vs <=69 in round 8: persistent
// environment/co-compile drift, not chased — cross-round deltas on
// co-compiled kernels are unreliable, rule #19.)
// C-write modes: 0 = row-major [M][N]; 1 = K head-major [bh][s][64];
// 2 = V 16-wide panels [bh][dh>>4][s][16]. SCQ: scale by SCQF before bf16 cast.
template <int N, int K, typename OT, int MODE, bool SCQ = false>
__device__ __forceinline__ void gemm128_body(const __hip_bfloat16* __restrict__ A,
                                             const __hip_bfloat16* __restrict__ W,
                                             OT* __restrict__ C, int bm, int bn,
                                             __hip_bfloat16* As, __hip_bfloat16* Bs) {
    const int tid  = threadIdx.x;
    const int wid  = tid >> 6;
    const int lane = tid & 63;
    const int quad = lane >> 4;
    const int l16  = lane & 15;
    const int wr = wid >> 1, wc = wid & 1;

    // staging: wave wid owns rows [wid*32, +32) of each tile, 4 calls x 8 rows.
    const int rlo = lane >> 3;                   // row within 8-row call
    const int xel = ((lane & 7) ^ rlo) * 8;      // pre-swizzled element offset
    const __hip_bfloat16* gA = A + (size_t)(bm * 128 + wid * 32 + rlo) * K + xel;
    const __hip_bfloat16* gB = W + (size_t)(bn * 128 + wid * 32 + rlo) * K + xel;
    __hip_bfloat16* lA = &As[(wid * 32) * 64];
    __hip_bfloat16* lB = &Bs[(wid * 32) * 64];

    const unsigned sw = (unsigned)((l16 & 7) << 4);  // read-side XOR (bytes)
    const char* Ap = (const char*)As;
    const char* Bp = (const char*)Bs;

    f32x4 acc[4][4] = {};

    for (int k0 = 0; k0 < K; k0 += 64) {
        __syncthreads();
#pragma unroll
        for (int c = 0; c < 4; ++c) {
            gl2lds16(gA + (size_t)(c * 8) * K + k0, lA + (c * 8) * 64);
            gl2lds16(gB + (size_t)(c * 8) * K + k0, lB + (c * 8) * 64);
        }
        __syncthreads();

#pragma unroll
        for (int kk = 0; kk < 2; ++kk) {
            bf16x8 af[4], bf[4];
#pragma unroll
            for (int mi = 0; mi < 4; ++mi)
                af[mi] = *reinterpret_cast<const bf16x8*>(
                    Ap + (wr * 64 + mi * 16 + l16) * 128 + ((kk * 64 + quad * 16) ^ sw));
#pragma unroll
            for (int ni = 0; ni < 4; ++ni)
                bf[ni] = *reinterpret_cast<const bf16x8*>(
                    Bp + (wc * 64 + ni * 16 + l16) * 128 + ((kk * 64 + quad * 16) ^ sw));
#pragma unroll
            for (int mi = 0; mi < 4; ++mi)
#pragma unroll
                for (int ni = 0; ni < 4; ++ni)
                    acc[mi][ni] = __builtin_amdgcn_mfma_f32_16x16x32_bf16(af[mi], bf[ni], acc[mi][ni], 0, 0, 0);
        }
    }

#pragma unroll
    for (int mi = 0; mi < 4; ++mi)
#pragma unroll
        for (int ni = 0; ni < 4; ++ni) {
            const int row0 = bm * 128 + wr * 64 + mi * 16 + quad * 4;
            const int col  = bn * 128 + wc * 64 + ni * 16 + l16;
#pragma unroll
            for (int r = 0; r < 4; ++r) {
                const int row = row0 + r;
                float v = acc[mi][ni][r];
                if constexpr (SCQ) v *= SCQF;
                if constexpr (MODE == 0) {
                    if constexpr (__is_same(OT, float))
                        C[(size_t)row * N + col] = v;
                    else
                        C[(size_t)row * N + col] = __float2bfloat16(v);
                } else if constexpr (MODE == 1) {
                    const int bh = (row >> 11) * Hz + (col >> 6);
                    C[(size_t)bh * (Sz * DHz) + (size_t)(row & 2047) * 64 + (col & 63)] =
                        __float2bfloat16(v);
                } else {
                    const int bh = (row >> 11) * Hz + (col >> 6);
                    C[(size_t)bh * (Sz * DHz) + (size_t)((col >> 4) & 3) * (Sz * 16) +
                      (size_t)(row & 2047) * 16 + (col & 15)] = __float2bfloat16(v);
                }
            }
        }
}

// Final GEMM with T1 XCD-chunk swizzle: each XCD gets a contiguous chunk of
// (bm,bn) tiles -> A chunk 2MB + wo 2MB fit its private 4MB L2.
template <int M, int N, int K, typename OT>
__global__ __launch_bounds__(256) void gemm128(const __hip_bfloat16* __restrict__ A,
                                               const __hip_bfloat16* __restrict__ W,
                                               OT* __restrict__ C) {
    __shared__ __hip_bfloat16 As[128 * 64];
    __shared__ __hip_bfloat16 Bs[128 * 64];
    constexpr int NB = N / 128;
    constexpr int NWG = (M / 128) * NB;          // 512, %8==0 -> bijective
    const int bid = blockIdx.x;
    const int swz = (bid & 7) * (NWG / 8) + (bid >> 3);
    gemm128_body<N, K, OT, 0>(A, W, C, swz / NB, swz % NB, As, Bs);
}

// Fused QKV with T1 XCD-chunk swizzle: semantic index s = rem*3 + which keeps
// the 3 GEMMs of one A-tile adjacent; chunking gives each XCD 64 consecutive
// (bm,bn) tiles (A chunk 8 panels = 2MB -> L2-resident per XCD).
template <int M, int K>
__global__ __launch_bounds__(256) void gemm_qkv(const __hip_bfloat16* __restrict__ A,
                                                const __hip_bfloat16* __restrict__ W0,
                                                const __hip_bfloat16* __restrict__ W1,
                                                const __hip_bfloat16* __restrict__ W2,
                                                __hip_bfloat16* __restrict__ C0,
                                                __hip_bfloat16* __restrict__ C1,
                                                __hip_bfloat16* __restrict__ C2) {
    __shared__ __hip_bfloat16 As[128 * 64];
    __shared__ __hip_bfloat16 Bs[128 * 64];
    constexpr int NB = Dz / 128;
    constexpr int NWG = 3 * (M / 128) * NB;      // 1536, %8==0 -> bijective
    const int bid = blockIdx.x;
    const int s   = (bid & 7) * (NWG / 8) + (bid >> 3);
    const int which = s % 3;
    const int rem   = s / 3;
    const int bm = rem / NB, bn = rem % NB;
    if (which == 0)      gemm128_body<Dz, K, __hip_bfloat16, 0, true>(A, W0, C0, bm, bn, As, Bs);
    else if (which == 1) gemm128_body<Dz, K, __hip_bfloat16, 1>(A, W1, C1, bm, bn, As, Bs);
    else                 gemm128_body<Dz, K, __hip_bfloat16, 2>(A, W2, C2, bm, bn, As, Bs);
}

// concat two 4x bf16 fragments into a K=32 8x bf16 fragment (register-only).
__device__ __forceinline__ bf16x8 cat8(s16x4 a, s16x4 b) {
    s16x8 t = __builtin_shufflevector(a, b, 0, 1, 2, 3, 4, 5, 6, 7);
    union { s16x8 s; bf16x8 h; } u; u.s = t; return u.h;
}

// HW transpose read: lane reads 8 CONSECUTIVE bytes at its own address; the
// transpose is a cross-lane exchange within each 16-lane group. With linear
// addresses base + lane*8 over a [16key][16dh] 512B subtile: lane(quad,l16)
// elem j = tile[quad*4+j][l16] (m156's layout; verified round 4).
#define TRD(i, off) \
    asm volatile("ds_read_b64_tr_b16 %0, %1 offset:" off : "=v"(vf[i]) : "v"(va))

// MFMA flash attention v9 — best verified attn (round 11, total 230.9us).
// v10's shared-K-stream (round 12) was neutral-to-negative (+3us total) with
// doubled register state -> reverted to this simpler structure per discipline.
//  - v6/v7 verified memory path: head-major K/V, block-shared glds staging,
//    XOR-swizzled K, tr-read V, double-buffered, one syncthreads/tile.
//  - K=32 PV fusion: 16x16x16 and 16x16x32 cost the same ~5 issue cycles; the
//    MFMA k-axis is contraction-order-invariant, so concatenating TR pairs and
//    matching P pairs halves PV+l MFMA count (28 -> 18/iter).
__global__ __launch_bounds__(256, 4) void attn_mfma9(const __hip_bfloat16* __restrict__ Q,
                                                     const __hip_bfloat16* __restrict__ Kh,
                                                     const __hip_bfloat16* __restrict__ Vh,
                                                     __hip_bfloat16* __restrict__ O) {
    __shared__ __hip_bfloat16 Ks[2][64 * 64];   // [key][dh], rows XOR-swizzled
    __shared__ __hip_bfloat16 Vs[2][64 * 64];   // [dh>>4][key][16] panels

    const int tid  = threadIdx.x;
    const int wid  = tid >> 6;
    const int lane = tid & 63;
    const int quad = lane >> 4;
    const int l16  = lane & 15;

    // XCD-local mapping: all 16 pair-blocks of a (b,h) share blockIdx%8 -> same XCD L2.
    const int xcd  = blockIdx.x & 7;
    const int j    = blockIdx.x >> 3;            // 0..127
    const int bh   = xcd * 8 + (j >> 4);         // 0..63
    const int pair = j & 15;
    const int h    = bh & 15;
    const int b    = bh >> 4;
    const size_t baseQ = (size_t)b * Sz * Dz + (size_t)h * DHz;   // Q/O row-major
    const size_t kvb   = (size_t)bh * (Sz * DHz);                 // K/V head-major

    // staging lane constants
    const int rlo = lane >> 3;                   // K: row-in-call
    const int xel = ((lane & 7) ^ rlo) * 8;      // K: pre-swizzled element offset

    auto stage = [&](int kn, int bf_) {
#pragma unroll
        for (int c = 0; c < 2; ++c) {
            // K: wave wid stages rows [wid*16+c*8, +8): 1KB coalesced, source pre-swizzled
            gl2lds16(Kh + kvb + (size_t)(kn + wid * 16 + c * 8 + rlo) * 64 + xel,
                     &Ks[bf_][(wid * 16 + c * 8) * 64]);
            // V: wave wid stages panel dh-group wid, keys [kn+c*32, +32): 1KB coalesced
            gl2lds16(Vh + kvb + (size_t)wid * (Sz * 16) + (size_t)(kn + c * 32 + (lane >> 1)) * 16 + (lane & 1) * 8,
                     &Vs[bf_][wid * 1024 + c * 512]);
        }
    };

    const unsigned vb0 = ldsaddr(&Vs[0][0]) + lane * 8;   // linear per-lane TR addr
    const unsigned sw  = (l16 & 7) << 4;         // read-side XOR for K rows

    union { s16x8 s; bf16x8 h; } onesu;
#pragma unroll
    for (int i = 0; i < 8; ++i) onesu.s[i] = (short)0x3F80;  // bf16 1.0 x8
    const bf16x8 ones8 = onesu.h;

    int buf = 0;
    stage(0, 0);                                  // prologue: tile 0 -> buf 0
    __syncthreads();

#pragma unroll 1
    for (int p = 0; p < 2; ++p) {
        const int qblk  = (p == 0) ? pair : 31 - pair;
        const int q0    = qblk * 64 + wid * 16;
        const int niter = qblk + 1;

        const __hip_bfloat16* qp = Q + baseQ + (size_t)(q0 + l16) * Dz + quad * 8;
        const bf16x8 qf0 = *reinterpret_cast<const bf16x8*>(qp);
        const bf16x8 qf1 = *reinterpret_cast<const bf16x8*>(qp + 32);

        float m = -1e30f;
        f32x4 ot[4] = {};                        // O^T: ot[sd][r] = O^T[dh=sd*16+quad*4+r][q=l16]
        f32x4 lacc  = {};                        // lacc[0] = running softmax denom for q=l16

#pragma unroll 1
        for (int it = 0; it < niter; ++it) {
            const int k0 = it * 64;

            // S^T = K·Q^T from swizzled Ks[buf]: 8 ds_read_b128 + 8 MFMA (K=32)
            f32x4 st[4] = {};
            {
                const char* Kp = (const char*)&Ks[buf][0];
#pragma unroll
                for (int s = 0; s < 4; ++s) {
                    const int rb = (s * 16 + l16) * 128;
                    const bf16x8 a0 = *reinterpret_cast<const bf16x8*>(Kp + rb + ((quad * 16) ^ sw));
                    const bf16x8 a1 = *reinterpret_cast<const bf16x8*>(Kp + rb + ((quad * 16 + 64) ^ sw));
                    st[s] = __builtin_amdgcn_mfma_f32_16x16x32_bf16(a0, qf0, st[s], 0, 0, 0);
                    st[s] = __builtin_amdgcn_mfma_f32_16x16x32_bf16(a1, qf1, st[s], 0, 0, 0);
                }
            }

            // stage next tile into buf^1 — glds latency hides under softmax+PV;
            // safe: barrier at prev iter end means nobody still reads buf^1.
            const bool more = (it + 1 < niter);
            if (more)        stage(k0 + 64, buf ^ 1);
            else if (p == 0) stage(0,       buf ^ 1);

            // scores already in log2 domain (Q pre-scaled); mask diagonal tile only
            float sv[16];
            if (it == niter - 1) {               // block-uniform branch
                const int qrow = q0 + l16;
#pragma unroll
                for (int s = 0; s < 4; ++s)
#pragma unroll
                    for (int r = 0; r < 4; ++r) {
                        const int key = k0 + s * 16 + quad * 4 + r;
                        sv[s * 4 + r] = (key <= qrow) ? st[s][r] : -1e30f;
                    }
            } else {
#pragma unroll
                for (int s = 0; s < 4; ++s)
#pragma unroll
                    for (int r = 0; r < 4; ++r) sv[s * 4 + r] = st[s][r];
            }

            // row max: max3-friendly triples, then cross-quad
            const float p0 = fmaxf(fmaxf(sv[0],  sv[1]),  sv[2]);
            const float p1 = fmaxf(fmaxf(sv[3],  sv[4]),  sv[5]);
            const float p2 = fmaxf(fmaxf(sv[6],  sv[7]),  sv[8]);
            const float p3 = fmaxf(fmaxf(sv[9],  sv[10]), sv[11]);
            const float p4 = fmaxf(fmaxf(sv[12], sv[13]), sv[14]);
            const float p5 = fmaxf(fmaxf(p0, p1), p2);
            float tmax = fmaxf(fmaxf(fmaxf(p5, p3), p4), sv[15]);
            tmax = fmaxf(tmax, __shfl_xor(tmax, 16, 64));
            tmax = fmaxf(tmax, __shfl_xor(tmax, 32, 64));

            const float mnew = fmaxf(m, tmax);
            const bool  skip = __all(tmax <= m); // alpha == 1 exactly -> skip rescale
            if (!skip) {
                const float alpha = __builtin_amdgcn_exp2f(m - mnew);
                m = mnew;
#pragma unroll
                for (int s = 0; s < 4; ++s) ot[s] *= alpha;  // own-lane alpha: q == l16
                lacc[0] *= alpha;                            // only element 0 is read
            }

            float pv[16];
#pragma unroll
            for (int i = 0; i < 16; ++i) pv[i] = __builtin_amdgcn_exp2f(sv[i] - m);

            // ---- lgkm-clean window: TR issues overlap pack + l-MFMA work ----
            s16x4 vf[16];
            const unsigned va = vb0 + (unsigned)(buf << 13);
            TRD(0, "0");    TRD(1, "512");  TRD(2, "1024"); TRD(3, "1536");
            TRD(4, "2048"); TRD(5, "2560"); TRD(6, "3072"); TRD(7, "3584");

            // P^T -> two K=32 bf16 fragments (s=0|1 and s=2|3 concatenated)
            union { s16x8 s; bf16x8 h; } u01, u23;
#pragma unroll
            for (int r = 0; r < 4; ++r) {
                union { __hip_bfloat16 hh; short uu; } c0, c1, c2, c3;
                c0.hh = __float2bfloat16(pv[r]);
                c1.hh = __float2bfloat16(pv[4 + r]);
                c2.hh = __float2bfloat16(pv[8 + r]);
                c3.hh = __float2bfloat16(pv[12 + r]);
                u01.s[r]     = c0.uu;
                u01.s[4 + r] = c1.uu;
                u23.s[r]     = c2.uu;
                u23.s[4 + r] = c3.uu;
            }
            const bf16x8 pw01 = u01.h;
            const bf16x8 pw23 = u23.h;

            // l-row-sum on the matrix pipe: lacc += ones · P^T  (2x K=32)
            lacc = __builtin_amdgcn_mfma_f32_16x16x32_bf16(ones8, pw01, lacc, 0, 0, 0);
            lacc = __builtin_amdgcn_mfma_f32_16x16x32_bf16(ones8, pw23, lacc, 0, 0, 0);

            asm volatile("s_waitcnt lgkmcnt(0)" ::: "memory");
            __builtin_amdgcn_sched_barrier(0);
            TRD(8,  "4096"); TRD(9,  "4608"); TRD(10, "5120"); TRD(11, "5632");
            TRD(12, "6144"); TRD(13, "6656"); TRD(14, "7168"); TRD(15, "7680");

            // PV sd0/sd1 at K=32 (covers second TR batch latency)
            ot[0] = __builtin_amdgcn_mfma_f32_16x16x32_bf16(cat8(vf[0],  vf[1]),  pw01, ot[0], 0, 0, 0);
            ot[0] = __builtin_amdgcn_mfma_f32_16x16x32_bf16(cat8(vf[2],  vf[3]),  pw23, ot[0], 0, 0, 0);
            ot[1] = __builtin_amdgcn_mfma_f32_16x16x32_bf16(cat8(vf[4],  vf[5]),  pw01, ot[1], 0, 0, 0);
            ot[1] = __builtin_amdgcn_mfma_f32_16x16x32_bf16(cat8(vf[6],  vf[7]),  pw23, ot[1], 0, 0, 0);

            asm volatile("s_waitcnt lgkmcnt(0)" ::: "memory");
            __builtin_amdgcn_sched_barrier(0);
            ot[2] = __builtin_amdgcn_mfma_f32_16x16x32_bf16(cat8(vf[8],  vf[9]),  pw01, ot[2], 0, 0, 0);
            ot[2] = __builtin_amdgcn_mfma_f32_16x16x32_bf16(cat8(vf[10], vf[11]), pw23, ot[2], 0, 0, 0);
            ot[3] = __builtin_amdgcn_mfma_f32_16x16x32_bf16(cat8(vf[12], vf[13]), pw01, ot[3], 0, 0, 0);
            ot[3] = __builtin_amdgcn_mfma_f32_16x16x32_bf16(cat8(vf[14], vf[15]), pw23, ot[3], 0, 0, 0);

            __syncthreads();   // drains our glds (vmcnt 0) + releases buffers
            buf ^= 1;
        }

        // epilogue: lane holds O^T[dh=sd*16+quad*4+r][q=l16]; lacc[0] is own-lane denom.
        const float linv = 1.f / lacc[0];
        __hip_bfloat16* op = O + baseQ + (size_t)(q0 + l16) * Dz + quad * 4;
#pragma unroll
        for (int sd = 0; sd < 4; ++sd) {
            u16x4 w;
#pragma unroll
            for (int r = 0; r < 4; ++r) {
                union { __hip_bfloat16 hh; unsigned short uu; } cv;
                cv.hh = __float2bfloat16(ot[sd][r] * linv);
                w[r] = cv.uu;
            }
            *reinterpret_cast<u16x4*>(op + sd * 16) = w;
        }
    }
}

extern "C" void kernel_launch(void* const* d_in, const int* in_sizes, int n_in,
                              void* d_out, int out_size, void* d_ws, size_t ws_size,
                              hipStream_t stream) {
    // Inputs fp32, output fp32. Internal compute bf16.
    const float* x  = (const float*)d_in[0];
    const float* wq = (const float*)d_in[1];
    const float* wk = (const float*)d_in[2];
    const float* wv = (const float*)d_in[3];
    const float* wo = (const float*)d_in[4];
    float* out = (float*)d_out;

    constexpr int TOK = Bz * Sz * Dz;   // 8,388,608
    constexpr int WEL = Dz * Dz;        // 1,048,576

    // ws: xb | wqb | wkb | wvb | wob | Qb | Kh (56 MB). Vh in d_out scratch; Ob aliases xb.
    __hip_bfloat16* xb  = (__hip_bfloat16*)d_ws;
    __hip_bfloat16* wqb = xb  + TOK;
    __hip_bfloat16* wkb = wqb + WEL;
    __hip_bfloat16* wvb = wkb + WEL;
    __hip_bfloat16* wob = wvb + WEL;
    __hip_bfloat16* Qb  = wob + WEL;
    __hip_bfloat16* Kh  = Qb + TOK;
    __hip_bfloat16* Vh  = (__hip_bfloat16*)d_out;  // dead before final GEMM overwrites d_out
    __hip_bfloat16* Ob  = xb;                      // x dead after QKV GEMM

    cvt_all<<<(TOK + 4 * WEL) / 4 / 256, 256, 0, stream>>>(x, wq, wk, wv, wo, xb);

    constexpr int M = Bz * Sz;                       // 8192
    constexpr int GB = (M / 128) * (Dz / 128);       // 512

    gemm_qkv<M, Dz><<<3 * GB, 256, 0, stream>>>(xb, wqb, wkb, wvb, Qb, Kh, Vh);

    const int ATTN_BLOCKS = Bz * Hz * 16;            // 1024 (paired 64-row q-blocks)
    attn_mfma9<<<ATTN_BLOCKS, 256, 0, stream>>>(Qb, Kh, Vh, Ob);

    gemm128<M, Dz, Dz, float><<<GB, 256, 0, stream>>>(Ob, wob, out);
}